// Round 6
// baseline (52.878 us; speedup 1.0000x reference)
//
#include <hip/hip_runtime.h>
#include <hip/hip_bf16.h>

// GridToMeshEncoder R6: fused kernel with XOR-swizzled LDS (T2) and
// register-hoisted gather loads.
//   phase1: vectorized gather (16 row loads hoisted) -> swizzled comb LDS
//   phase2: GEMM1 h^T = W1^T * comb^T (mfma 16x16x32 bf16) -> swizzled hbuf
//   phase3: GEMM2^T out^T = W2^T * h^T -> float4 stores
// prep kernel packs W1/W2 into MFMA fragment order (L2-resident, ~180 KB).

constexpr int kNLat  = 721;
constexpr int kNLon  = 1440;
constexpr long long kNPix = (long long)kNLat * kNLon;   // 1038240
constexpr int kMesh  = 40962;
constexpr int kCIn   = 64;
constexpr int kFeat  = 4;
constexpr int kDIn   = kCIn + kFeat;                    // 68
constexpr int kHid   = 256;
constexpr int kOut   = 256;
constexpr int kBatch = 2;

constexpr int kPts    = kBatch * kMesh;                 // 81924
constexpr int kPtsPad = (kPts + 63) & ~63;              // 81984

typedef __attribute__((ext_vector_type(8))) short bf16x8;
typedef __attribute__((ext_vector_type(4))) float f32x4;

// ws layout (ushort units): wsA1 = W1^T A-frags [rt:16][ks:3][lane:64][j:8]
//                           wsB2 = W2   frags   [ct:16][ks:8][lane:64][j:8]
constexpr int    WSA1_N   = 16 * 3 * 64 * 8;            // 24576
constexpr int    WSB2_N   = 16 * 8 * 64 * 8;            // 65536
constexpr size_t WS_BYTES = (size_t)(WSA1_N + WSB2_N) * 2;  // 180224

constexpr int MP    = 64;                       // points per block
constexpr int NBLKB = kPtsPad / MP;             // 1281
constexpr int CSTR  = 128;                      // comb row stride (ushort): 256 B
constexpr int HSTR  = 256;                      // hbuf row stride (ushort): 512 B

__device__ inline ushort f2b(float v) {
    __hip_bfloat16 h = __float2bfloat16(v);
    return *reinterpret_cast<ushort*>(&h);
}

// XOR swizzle: rows land 0 mod 32 banks; XOR row bits into 16B-granule index
// so each quarter-wave's 16 rows spread across all 32 banks (<=2-way, free).
__device__ inline int cswz(int r, int c) { return r * CSTR + (c ^ ((r & 7) << 3)); }
__device__ inline int hswz(int r, int c) { return r * HSTR + (c ^ ((r & 7) << 3)); }

// ---------------- prep: pack W1/W2 into frag-ordered bf16 ----------------
__global__ __launch_bounds__(256)
void g2m_prep(const float* __restrict__ W1, const float* __restrict__ W2,
              ushort* __restrict__ ws) {
    const int tid = blockIdx.x * 256 + threadIdx.x;
    if (tid < 3072) {                       // wsA1: A[i=hid][k] = W1[k][hid]
        const int l  = tid & 63;
        const int g  = tid >> 6;            // g = rt*3 + ks
        const int ks = g % 3;
        const int rt = g / 3;
        const int hid = rt * 16 + (l & 15);
        const int k0  = ks * 32 + (l >> 4) * 8;
        ushort tmp[8];
        #pragma unroll
        for (int j = 0; j < 8; ++j) {
            const int k = k0 + j;
            tmp[j] = f2b(k < kDIn ? W1[(size_t)k * kHid + hid] : 0.f);
        }
        *reinterpret_cast<bf16x8*>(ws + (size_t)tid * 8) =
            *reinterpret_cast<bf16x8*>(tmp);
    } else if (tid < 11264) {               // wsB2: [ct][ks][lane][8] = W2[k][col]
        const int q  = tid - 3072;
        const int l  = q & 63;
        const int g  = q >> 6;              // g = ct*8 + ks
        const int ks = g % 8;
        const int ct = g / 8;
        const int col = ct * 16 + (l & 15);
        const int k0  = ks * 32 + (l >> 4) * 8;
        ushort tmp[8];
        #pragma unroll
        for (int j = 0; j < 8; ++j) {
            const int k = k0 + j;
            tmp[j] = f2b(W2[(size_t)k * kOut + col]);
        }
        *reinterpret_cast<bf16x8*>(ws + (size_t)(WSA1_N + q * 8)) =
            *reinterpret_cast<bf16x8*>(tmp);
    }
}

// ---------------- fused: gather -> GEMM1 -> GEMM2^T -> out ----------------
__global__ __launch_bounds__(256, 3)
void g2m_fused3(const float* __restrict__ grid,
                const float* __restrict__ mfeat,
                const int*   __restrict__ indices,
                const float* __restrict__ weights,
                const float* __restrict__ b1,
                const float* __restrict__ b2,
                const ushort* __restrict__ ws,
                float* __restrict__ out)
{
    __shared__ __align__(16) ushort comb[MP * CSTR];    // 16384 B
    __shared__ __align__(16) ushort hbuf[MP * HSTR];    // 32768 B

    const int t    = threadIdx.x;
    const int lane = t & 63;
    const int w    = t >> 6;                    // wave id 0..3
    const int p0   = blockIdx.x * MP;
    const int l15  = lane & 15;
    const int l4   = lane >> 4;

    // ---- phase 1: gather, all 16 row loads hoisted into registers ----
    {
        const int q = l4;                       // point-in-group 0..3
        float4 rr[4][4];
        float4 wtv[4];
        float  mf0[4], mf1[4];

        #pragma unroll
        for (int it = 0; it < 4; ++it) {
            const int p = p0 + w * 16 + it * 4 + q;
            rr[it][0] = rr[it][1] = rr[it][2] = rr[it][3] = float4{0.f, 0.f, 0.f, 0.f};
            wtv[it] = float4{0.f, 0.f, 0.f, 0.f};
            mf0[it] = 0.f; mf1[it] = 0.f;
            if (p < kPts) {
                const int b = (p >= kMesh) ? 1 : 0;
                const int m = p - b * kMesh;
                const int4 id = *reinterpret_cast<const int4*>(indices + (size_t)m * 4);
                wtv[it] = *reinterpret_cast<const float4*>(weights + (size_t)m * 4);
                const float* gb = grid + (size_t)b * (size_t)(kNPix * kCIn);
                rr[it][0] = *reinterpret_cast<const float4*>(gb + (size_t)id.x * kCIn + l15 * 4);
                rr[it][1] = *reinterpret_cast<const float4*>(gb + (size_t)id.y * kCIn + l15 * 4);
                rr[it][2] = *reinterpret_cast<const float4*>(gb + (size_t)id.z * kCIn + l15 * 4);
                rr[it][3] = *reinterpret_cast<const float4*>(gb + (size_t)id.w * kCIn + l15 * 4);
                if (l15 < 2) {
                    mf0[it] = mfeat[(size_t)m * kFeat + l15 * 2];
                    mf1[it] = mfeat[(size_t)m * kFeat + l15 * 2 + 1];
                }
            }
        }

        #pragma unroll
        for (int it = 0; it < 4; ++it) {
            const int row = w * 16 + it * 4 + q;
            const float4 wt = wtv[it];
            float4 acc;
            acc.x = fmaf(wt.x, rr[it][0].x, fmaf(wt.y, rr[it][1].x, fmaf(wt.z, rr[it][2].x, wt.w * rr[it][3].x)));
            acc.y = fmaf(wt.x, rr[it][0].y, fmaf(wt.y, rr[it][1].y, fmaf(wt.z, rr[it][2].y, wt.w * rr[it][3].y)));
            acc.z = fmaf(wt.x, rr[it][0].z, fmaf(wt.y, rr[it][1].z, fmaf(wt.z, rr[it][2].z, wt.w * rr[it][3].z)));
            acc.w = fmaf(wt.x, rr[it][0].w, fmaf(wt.y, rr[it][1].w, fmaf(wt.z, rr[it][2].w, wt.w * rr[it][3].w)));
            ushort4 pk;
            pk.x = f2b(acc.x); pk.y = f2b(acc.y); pk.z = f2b(acc.z); pk.w = f2b(acc.w);
            *reinterpret_cast<ushort4*>(&comb[cswz(row, l15 * 4)]) = pk;   // cols 0..63
            ushort2 ft;                                                     // cols 64..95
            ft.x = f2b(mf0[it]); ft.y = f2b(mf1[it]);
            *reinterpret_cast<ushort2*>(&comb[cswz(row, 64 + l15 * 2)]) = ft;
        }
    }
    __syncthreads();

    // ---- phase 2: GEMM1  h^T = W1^T @ comb^T ----
    {
        f32x4 acc1[4][4];                       // [r(hid-tile)][mt(pt-tile)]
        #pragma unroll
        for (int r = 0; r < 4; ++r)
            #pragma unroll
            for (int mt = 0; mt < 4; ++mt) acc1[r][mt] = (f32x4)0.f;

        #pragma unroll
        for (int ks = 0; ks < 3; ++ks) {
            bf16x8 af[4], bfr[4];
            #pragma unroll
            for (int r = 0; r < 4; ++r) {
                const int rt = w * 4 + r;
                af[r] = *reinterpret_cast<const bf16x8*>(
                            ws + (size_t)((rt * 3 + ks) * 64 + lane) * 8);
            }
            #pragma unroll
            for (int mt = 0; mt < 4; ++mt)
                bfr[mt] = *reinterpret_cast<const bf16x8*>(
                            &comb[cswz(mt * 16 + l15, ks * 32 + l4 * 8)]);
            #pragma unroll
            for (int r = 0; r < 4; ++r)
                #pragma unroll
                for (int mt = 0; mt < 4; ++mt)
                    acc1[r][mt] = __builtin_amdgcn_mfma_f32_16x16x32_bf16(
                                      af[r], bfr[mt], acc1[r][mt], 0, 0, 0);
        }

        // bias + relu -> hbuf[m][hid] (bf16, swizzled)
        #pragma unroll
        for (int r = 0; r < 4; ++r) {
            const int hid0 = (w * 4 + r) * 16 + l4 * 4;
            const float4 bv = *reinterpret_cast<const float4*>(b1 + hid0);
            #pragma unroll
            for (int mt = 0; mt < 4; ++mt) {
                const int m = mt * 16 + l15;
                ushort4 hv;
                hv.x = f2b(fmaxf(acc1[r][mt][0] + bv.x, 0.f));
                hv.y = f2b(fmaxf(acc1[r][mt][1] + bv.y, 0.f));
                hv.z = f2b(fmaxf(acc1[r][mt][2] + bv.z, 0.f));
                hv.w = f2b(fmaxf(acc1[r][mt][3] + bv.w, 0.f));
                *reinterpret_cast<ushort4*>(&hbuf[hswz(m, hid0)]) = hv;
            }
        }
    }
    __syncthreads();

    // ---- phase 3: GEMM2 transposed  out^T = W2^T @ h^T ----
    {
        f32x4 acc2[4][4];                       // [mt(pt-tile)][c(outcol-tile)]
        #pragma unroll
        for (int mt = 0; mt < 4; ++mt)
            #pragma unroll
            for (int c = 0; c < 4; ++c) acc2[mt][c] = (f32x4)0.f;

        #pragma unroll
        for (int ks = 0; ks < 8; ++ks) {
            bf16x8 hf[4], wf[4];
            #pragma unroll
            for (int mt = 0; mt < 4; ++mt)
                hf[mt] = *reinterpret_cast<const bf16x8*>(
                            &hbuf[hswz(mt * 16 + l15, ks * 32 + l4 * 8)]);
            #pragma unroll
            for (int c = 0; c < 4; ++c) {
                const int ct = w * 4 + c;
                wf[c] = *reinterpret_cast<const bf16x8*>(
                            ws + (size_t)(WSA1_N + ((ct * 8 + ks) * 64 + lane) * 8));
            }
            #pragma unroll
            for (int mt = 0; mt < 4; ++mt)
                #pragma unroll
                for (int c = 0; c < 4; ++c)
                    acc2[mt][c] = __builtin_amdgcn_mfma_f32_16x16x32_bf16(
                                      wf[c], hf[mt], acc2[mt][c], 0, 0, 0);
        }

        // epilogue: lane holds 4 consecutive out cols for one point -> float4
        #pragma unroll
        for (int c = 0; c < 4; ++c) {
            const int col0 = (w * 4 + c) * 16 + l4 * 4;
            const float4 bv = *reinterpret_cast<const float4*>(b2 + col0);
            #pragma unroll
            for (int mt = 0; mt < 4; ++mt) {
                const int p = p0 + mt * 16 + l15;
                if (p < kPts) {
                    float4 o;
                    o.x = acc2[mt][c][0] + bv.x;
                    o.y = acc2[mt][c][1] + bv.y;
                    o.z = acc2[mt][c][2] + bv.z;
                    o.w = acc2[mt][c][3] + bv.w;
                    *reinterpret_cast<float4*>(out + (size_t)p * kOut + col0) = o;
                }
            }
        }
    }
}

extern "C" void kernel_launch(void* const* d_in, const int* in_sizes, int n_in,
                              void* d_out, int out_size, void* d_ws, size_t ws_size,
                              hipStream_t stream) {
    const float* grid    = (const float*)d_in[0];
    const float* mfeat   = (const float*)d_in[1];
    const int*   indices = (const int*)d_in[2];
    const float* weights = (const float*)d_in[3];
    const float* W1      = (const float*)d_in[4];
    const float* b1      = (const float*)d_in[5];
    const float* W2      = (const float*)d_in[6];
    const float* b2      = (const float*)d_in[7];
    float* o = (float*)d_out;

    if (ws_size >= WS_BYTES) {
        ushort* ws = (ushort*)d_ws;
        g2m_prep<<<44, 256, 0, stream>>>(W1, W2, ws);
        g2m_fused3<<<NBLKB, 256, 0, stream>>>(grid, mfeat, indices, weights,
                                              b1, b2, ws, o);
    }
}